// Round 9
// baseline (335.846 us; speedup 1.0000x reference)
//
#include <hip/hip_runtime.h>
#include <hip/hip_bf16.h>
#include <hip/hip_fp16.h>
#include <stdint.h>

#define NN 100000
#define NT 2000000
#define HD 48
#define VS 64                     // vh row stride in halfs (128 B, line-aligned)
#define CAP 56                    // per-center bucket capacity; P(Poisson(20) >= 56) ~ 4e-10
#define NPB 20                    // nodes per fused-node block (NN % 20 == 0)
#define NBH ((NT + 255) / 256)
#define NB ((NN + 1023) / 1024)   // 98 scan blocks (fallback)

// ---- superbin pipeline (primary path) ----
#define BINB 64                       // centers per accum bin
#define NBIN ((NN + BINB - 1) / BINB) // 1563 accum bins
#define SBB 256                       // centers per scatter superbin
#define NSB ((NN + SBB - 1) / SBB)    // 391 superbins
#define SBCAP 6144                    // metas/superbin: mean 5120, sigma 71.5 -> +14.3σ
#define CHK 8192                      // triples per scatter block
#define NCHK ((NT + CHK - 1) / CHK)   // 245
#define NNODEB (NN / NPB)             // 5000 node tiles
#define FATGRID (NCHK + NNODEB)       // scatter blocks first (long), node blocks fill

// weight encoding: w = qw * (1.3/32767); real triples give qw in [25206,32767].
#define WSCALE (1.3f / 32767.0f)
#define WQUANT (32767.0f / 1.3f)

typedef _Float16 hf2 __attribute__((ext_vector_type(2)));

__device__ __forceinline__ float b2f(__hip_bfloat16 x) { return __bfloat162float(x); }

// Load a "float tensor" element whose storage is bf16 (flag=1) or f32 (flag=0).
__device__ __forceinline__ float ldf(const void* p, long long i, int isbf16) {
    if (isbf16) return b2f(((const __hip_bfloat16*)p)[i]);
    return ((const float*)p)[i];
}

__device__ __forceinline__ hf2 habs2(hf2 x) {
    union { hf2 h; unsigned int u; } c; c.h = x; c.u &= 0x7FFF7FFFu; return c.h;
}
__device__ __forceinline__ hf2 splat2(float f) {
    hf2 r; r.x = (_Float16)f; r.y = (_Float16)f; return r;
}
union V4H { uint4 u; hf2 h[4]; };

// ---------------------------------------------------------------------------
// prep (9 blocks): self-probe dtypes, fold weights, zero gcur.
// wu1f[o][k] = Wu[o][k];  bf[o][k] = sum_j Wu[o][48+j] * W3[j][k]
// ---------------------------------------------------------------------------
__global__ __launch_bounds__(256) void prep_kernel(
        const unsigned int* __restrict__ hw, const unsigned int* __restrict__ iw,
        int* __restrict__ flags,
        const void* __restrict__ W3, const void* __restrict__ Wu,
        float* __restrict__ wu1f, float* __restrict__ bf,
        int* __restrict__ gcur) {
    __shared__ int cbf, cix;
    int tid = threadIdx.x;
    if (tid == 0) { cbf = 0; cix = 0; }
    __syncthreads();
    unsigned int e = (hw[tid] >> 7) & 0xff;       // exponent of low-half bf16
    if (e >= 90 && e <= 144) atomicAdd(&cbf, 1);
    if (blockIdx.x == 0 && iw[2 * tid + 1] == 0) atomicAdd(&cix, 1);
    __syncthreads();
    int fb = (cbf >= 192) ? 1 : 0;                // bf16 ~256 hits; f32 ~55
    if (blockIdx.x == 0 && tid == 0) {
        flags[0] = fb;
        flags[1] = (cix >= 255) ? 1 : 0;          // int64 high words all zero
    }
    for (int i = blockIdx.x * 256 + tid; i < NSB * 32; i += 9 * 256)
        gcur[i] = 0;
    int i = blockIdx.x * 256 + tid;
    if (i < HD * HD) {
        int o = i / HD, hh = i % HD;
        wu1f[i] = ldf(Wu, o * 2 * HD + hh, fb);
        float s = 0.f;
        #pragma unroll 8
        for (int k = 0; k < HD; ++k)
            s += ldf(Wu, o * 2 * HD + HD + k, fb) * ldf(W3, k * HD + hh, fb);
        bf[i] = s;
    }
}

// ---------------------------------------------------------------------------
// fused_nb (primary): superbin scatter and node-transform are DATA-
// INDEPENDENT; one fat kernel runs both. Blocks 0..NCHK-1 = scatter chunks
// (long, start first); blocks NCHK.. = 20-node tiles filling the rest.
//
// scatter part (R8 post-mortem redesign): SINGLE-PHASE. The R5-R8 two-phase
// (histogram -> reserve -> scatter) forms all kept ~100us because 8 decoded
// triples must live across two barriers -> scratch demotion (VGPR 20-24
// with 32+ live values; WRITE_SIZE 72-95MB varying = spill + partial-line
// writeback). Now each triple completes in-loop: decode -> ONE global
// atomicAdd(&gcur[sb<<5],1) -> store at sb*SBCAP+pos. No LDS, no barriers,
// no cross-iteration liveness. 391 line-padded counters stay L2-resident;
// arrival-ordered slots make consecutive winners write consecutive
// addresses -> full-line combining (R0's center-granularity version lost
// to 64B-line amplification; 256-center superbins fix that).
// meta: x = n1 | qw15<<17 ; y = n2 | (c&255)<<17
//
// node part: u[n]=Wu1*h[n] (fp16 stride-48), v[n]=M*h[n] (fp16 stride-64 =
// 128 B line-aligned rows, dims 48..63 zeroed so gathers are single-line).
// ---------------------------------------------------------------------------
__global__ __launch_bounds__(1024) void fused_nb_kernel(
        const void* __restrict__ h, const int* __restrict__ flags,
        const float* __restrict__ wu1f, const float* __restrict__ bf,
        __half* __restrict__ uh, __half* __restrict__ vh,
        const void* __restrict__ idxp,
        const void* __restrict__ d1p, const void* __restrict__ d2p,
        int* __restrict__ gcur, uint2* __restrict__ binned) {
    __shared__ float Ws[HD * 49];
    __shared__ float Bs[HD * 49];
    __shared__ float hs[NPB * HD];
    int tid = threadIdx.x;
    int fb = flags[0];

    if (blockIdx.x < NCHK) {
        // ---------------- scatter part (no LDS, no barriers) ----------------
        int fi = flags[1];
        int t0 = blockIdx.x * CHK;
        const int* qi = (const int*)idxp;         // int64: low words at even idx
        #pragma unroll
        for (int j = 0; j < CHK / 1024; ++j) {
            int t = t0 + j * 1024 + tid;
            if (t >= NT) continue;
            int c, n1, n2;
            if (fi) {
                c  = qi[6LL * t];
                n1 = qi[6LL * t + 2];
                n2 = qi[6LL * t + 4];
            } else {
                c  = qi[3LL * t];
                n1 = qi[3LL * t + 1];
                n2 = qi[3LL * t + 2];
            }
            float d1 = ldf(d1p, t, fb);
            float d2 = ldf(d2p, t, fb);
            float asym = fabsf(d1 - d2) / (fmaxf(d1, d2) + 1e-8f);
            unsigned qw = (unsigned)((1.0f + 0.3f * asym) * WQUANT + 0.5f);
            if (qw > 32767u) qw = 32767u;
            int sb = c >> 8;
            int r = atomicAdd(&gcur[sb << 5], 1);
            if (r < SBCAP)
                binned[(size_t)sb * SBCAP + r] =
                    make_uint2((unsigned)n1 | (qw << 17),
                               (unsigned)n2 | ((unsigned)(c & 255) << 17));
        }
    } else {
        // ---------------- node part ----------------
        int base = (blockIdx.x - NCHK) * NPB;     // NN % 20 == 0
        for (int i = tid; i < HD * HD; i += 1024) {
            int o = i / HD, hh = i % HD;
            Ws[o * 49 + hh] = wu1f[i];
            Bs[o * 49 + hh] = bf[i];
        }
        for (int i = tid; i < NPB * HD; i += 1024)
            hs[i] = ldf(h, (long long)base * HD + i, fb);
        if (tid < NPB * 16) {  // zero the vh pad dims 48..63
            int ln = tid >> 4, o = HD + (tid & 15);
            vh[(size_t)(base + ln) * VS + o] = (__half)0.f;
        }
        __syncthreads();
        for (int i = tid; i < NPB * HD; i += 1024) {
            int ln = i / HD, o = i - ln * HD;
            const float* hr = hs + ln * HD;
            const float* wr = Ws + o * 49;
            const float* br = Bs + o * 49;
            float su = 0.f, sv = 0.f;
            #pragma unroll
            for (int k = 0; k < HD; ++k) { float hv = hr[k]; su += wr[k] * hv; sv += br[k] * hv; }
            int n = base + ln;
            uh[(size_t)n * HD + o] = __float2half(su);
            vh[(size_t)n * VS + o] = __float2half(sv);
        }
    }
}

// ---------------------------------------------------------------------------
// bin_accum (primary): one block per 64-center accum bin. The bin reads its
// SUPERBIN's metas (sb = bin>>2) and keeps those in its 64-center group
// ((c&255)>>6 == bin&3) -- 4x read amplification on the 19MB meta array,
// served by L2/L3 (~+4us), in exchange for the single-phase scatter.
// LDS-atomic scatter into per-center buckets (rows padded to 64), then the
// proven per-wave accum (R5 form: 16 triples/trip, FOUR gathers issued
// back-to-back; validity selects give w=0/row-0 for tail slots):
// lane=(s 0..7, dg 0..7), single-line uint4 gathers of 8 fp16 dims,
// packed-fp16 leaky(p)*w = (.505w)p + (.495w)|p|, drained to f32 per trip.
// Fused residual + LayerNorm epilogue. 8 waves x 8 centers each.
// LDS = 36.6 KB -> 4 blocks/CU (32 waves/CU).
// NOTE (R3/R6 post-mortems): do NOT hand-pipeline (R3: 79->105us) and do
// NOT widen to 32-trip/8-gather (R6: 78.6->81.5us, VGPR 40, Occ -11pts).
// The 16-trip straight-line 4-gather block is a verified local optimum.
// ---------------------------------------------------------------------------
__global__ __launch_bounds__(512, 4) void bin_accum_kernel(
        const void* __restrict__ h, const int* __restrict__ flags,
        const __half* __restrict__ uh, const __half* __restrict__ vh,
        const int* __restrict__ gcur, const uint2* __restrict__ binned,
        const void* __restrict__ gamma, const void* __restrict__ beta,
        void* __restrict__ out) {
    __shared__ uint2 buckets[BINB][64];           // 32768 B, 56 slots used
    __shared__ int   cur[BINB];
    __shared__ float ucs[8][64];
    __shared__ float accs[8][HD];
    int tid = threadIdx.x, fb = flags[0];
    int bin = blockIdx.x;
    int sb = bin >> 2;
    unsigned grp = (unsigned)(bin & 3);

    for (int i = tid; i < BINB; i += 512) cur[i] = 0;
    __syncthreads();

    int nm = gcur[sb << 5]; if (nm > SBCAP) nm = SBCAP;
    const uint2* bp = binned + (size_t)sb * SBCAP;
    for (int i = tid; i < nm; i += 512) {         // filtered LDS bucket scatter
        uint2 m = bp[i];
        unsigned cc = (m.y >> 17) & 255u;
        if ((cc >> 6) == grp) {
            int cl = (int)(cc & 63u);
            int r = atomicAdd(&cur[cl], 1);
            if (r < CAP) buckets[cl][r] = m;
        }
    }
    __syncthreads();

    int wv = tid >> 6, lane = tid & 63;
    int s = lane >> 3, dg = lane & 7;
    const char* vb = (const char*)vh;
    size_t dgo = (size_t)dg * 16;
    float gv = (lane < HD) ? ldf(gamma, lane, fb) : 0.f;
    float bv = (lane < HD) ? ldf(beta, lane, fb) : 0.f;

    for (int ci = 0; ci < BINB / 8; ++ci) {       // 8 centers per wave
        int cl = wv * (BINB / 8) + ci;
        int n = bin * BINB + cl;
        if (n >= NN) continue;                    // last bin: tail centers

        int m = cur[cl]; if (m > CAP) m = CAP;
        float hval = (lane < HD) ? ldf(h, (long long)n * HD + lane, fb) : 0.f;
        float uval = (lane < HD) ? __half2float(uh[(size_t)n * HD + lane]) : 0.f;
        ucs[wv][lane] = uval;                     // wave-sync write->read
        hf2 uc4[4];
        #pragma unroll
        for (int j = 0; j < 4; ++j) {
            uc4[j].x = (_Float16)ucs[wv][dg * 8 + 2 * j];
            uc4[j].y = (_Float16)ucs[wv][dg * 8 + 2 * j + 1];
        }

        float accf[8] = {0.f, 0.f, 0.f, 0.f, 0.f, 0.f, 0.f, 0.f};
        for (int t = 0; t < m; t += 16) {
            uint2 m0 = buckets[cl][t + s];        // in padded row, LDS-safe
            uint2 m1 = buckets[cl][t + 8 + s];
            int v0 = (t + s) < m, v1 = (t + 8 + s) < m;
            unsigned a0 = v0 ? (m0.x & 0x1FFFFu) : 0u;
            unsigned b0 = v0 ? (m0.y & 0x1FFFFu) : 0u;
            float w0 = v0 ? (float)(m0.x >> 17) * WSCALE : 0.f;
            unsigned a1 = v1 ? (m1.x & 0x1FFFFu) : 0u;
            unsigned b1 = v1 ? (m1.y & 0x1FFFFu) : 0u;
            float w1 = v1 ? (float)(m1.x >> 17) * WSCALE : 0.f;
            V4H pa0, pb0, pa1, pb1;
            pa0.u = *(const uint4*)(vb + (size_t)a0 * 128 + dgo);
            pb0.u = *(const uint4*)(vb + (size_t)b0 * 128 + dgo);
            pa1.u = *(const uint4*)(vb + (size_t)a1 * 128 + dgo);
            pb1.u = *(const uint4*)(vb + (size_t)b1 * 128 + dgo);
            hf2 aw0 = splat2(0.505f * w0), bw0 = splat2(0.495f * w0);
            hf2 aw1 = splat2(0.505f * w1), bw1 = splat2(0.495f * w1);
            #pragma unroll
            for (int j = 0; j < 4; ++j) {
                hf2 p0 = pa0.h[j] + pb0.h[j] + uc4[j];
                hf2 acch = p0 * aw0 + habs2(p0) * bw0;
                hf2 p1 = pa1.h[j] + pb1.h[j] + uc4[j];
                acch += p1 * aw1 + habs2(p1) * bw1;
                accf[2 * j]     += (float)acch.x;
                accf[2 * j + 1] += (float)acch.y;
            }
        }

        // reduce across the 8 slot-copies (lane bits 3..5)
        #pragma unroll
        for (int j = 0; j < 8; ++j) {
            accf[j] += __shfl_xor(accf[j], 8, 64);
            accf[j] += __shfl_xor(accf[j], 16, 64);
            accf[j] += __shfl_xor(accf[j], 32, 64);
        }
        if (lane < 6) {                           // dims 0..47
            #pragma unroll
            for (int j = 0; j < 8; ++j) accs[wv][lane * 8 + j] = accf[j];
        }
        float av = (lane < HD) ? accs[wv][lane] : 0.f; // wave-sync

        float rnc = rsqrtf(fmaxf((float)m, 1.0f));
        float x = (lane < HD) ? (hval + av * rnc) : 0.f;
        float su = x, sq = x * x;
        #pragma unroll
        for (int o = 32; o; o >>= 1) {
            su += __shfl_xor(su, o, 64);
            sq += __shfl_xor(sq, o, 64);
        }
        float mu   = su * (1.0f / HD);
        float var  = sq * (1.0f / HD) - mu * mu;
        float rstd = rsqrtf(var + 1e-5f);
        if (lane < HD) {
            float r = (x - mu) * rstd * gv + bv;
            if (fb) ((__hip_bfloat16*)out)[(size_t)n * HD + lane] = __float2bfloat16(r);
            else    ((float*)out)[(size_t)n * HD + lane] = r;
        }
    }
}

// ---------------------------------------------------------------------------
// node (fallback only): u[n]=Wu1*h[n], v[n]=M*h[n].
// ---------------------------------------------------------------------------
__global__ __launch_bounds__(256) void node_kernel(
        const void* __restrict__ h, const int* __restrict__ flags,
        const float* __restrict__ wu1f, const float* __restrict__ bf,
        __half* __restrict__ uh, __half* __restrict__ vh) {
    __shared__ float Ws[HD * 49];
    __shared__ float Bs[HD * 49];
    __shared__ float hs[16 * HD];
    int tid = threadIdx.x;
    int fb = flags[0];
    for (int i = tid; i < HD * HD; i += 256) {
        int o = i / HD, hh = i % HD;
        Ws[o * 49 + hh] = wu1f[i];
        Bs[o * 49 + hh] = bf[i];
    }
    int base = blockIdx.x * 16;                   // NN % 16 == 0
    for (int i = tid; i < 16 * HD; i += 256)
        hs[i] = ldf(h, (long long)base * HD + i, fb);
    {   // zero the vh pad dims 48..63
        int ln = tid >> 4, o = HD + (tid & 15);
        vh[(size_t)(base + ln) * VS + o] = (__half)0.f;
    }
    __syncthreads();
    for (int i = tid; i < 16 * HD; i += 256) {
        int ln = i / HD, o = i - ln * HD;
        const float* hr = hs + ln * HD;
        const float* wr = Ws + o * 49;
        const float* br = Bs + o * 49;
        float su = 0.f, sv = 0.f;
        #pragma unroll
        for (int k = 0; k < HD; ++k) { float hv = hr[k]; su += wr[k] * hv; sv += br[k] * hv; }
        int n = base + ln;
        uh[(size_t)n * HD + o] = __float2half(su);
        vh[(size_t)n * VS + o] = __float2half(sv);
    }
}

// ---------------------------------------------------------------------------
// hist (fallback only): line-padded counters cnt[c<<4].
// ---------------------------------------------------------------------------
__global__ __launch_bounds__(256) void hist_kernel(const void* __restrict__ idxp,
                                                   const int* __restrict__ flags,
                                                   int* __restrict__ cnt) {
    int t = blockIdx.x * 256 + threadIdx.x;
    if (t >= NT) return;
    int c = flags[1] ? (int)((const long long*)idxp)[3LL * t]
                     : ((const int*)idxp)[3 * t];
    atomicAdd(&cnt[c << 4], 1);
}

// ---------------------------------------------------------------------------
// scans (fallback only): exclusive scan of cnt[i<<4] -> off[NN].
// ---------------------------------------------------------------------------
__global__ __launch_bounds__(1024) void scan_part(const int* __restrict__ cnt,
                                                  int* __restrict__ off,
                                                  int* __restrict__ bsum) {
    __shared__ int wsums[16];
    int tid = threadIdx.x, lane = tid & 63, wv = tid >> 6;
    int i = blockIdx.x * 1024 + tid;
    int x = (i < NN) ? cnt[i << 4] : 0;
    int vx = x;
    #pragma unroll
    for (int o = 1; o < 64; o <<= 1) {
        int y = __shfl_up(vx, o, 64);
        if (lane >= o) vx += y;
    }
    if (lane == 63) wsums[wv] = vx;
    __syncthreads();
    if (tid == 0) {
        int s = 0;
        #pragma unroll
        for (int k = 0; k < 16; ++k) { int t2 = wsums[k]; wsums[k] = s; s += t2; }
        bsum[blockIdx.x] = s;
    }
    __syncthreads();
    if (i < NN) off[i] = wsums[wv] + vx - x;
}

__global__ __launch_bounds__(1024) void scan_add(int* __restrict__ off,
                                                 const int* __restrict__ bsum) {
    int bid = blockIdx.x;
    int pre = 0;
    for (int k = 0; k < bid; ++k) pre += bsum[k];
    int i = bid * 1024 + threadIdx.x;
    if (i < NN) off[i] += pre;
}

// ---------------------------------------------------------------------------
// scatter (fallback only): meta = uint2{ n1 | qw<<17, n2 }.
// pos = atomicAdd(&off[c],1)  (off -> inclusive end)
// ---------------------------------------------------------------------------
__global__ __launch_bounds__(256) void scatter_kernel(
        const void* __restrict__ idxp,
        const void* __restrict__ d1p, const void* __restrict__ d2p,
        const int* __restrict__ flags, int* __restrict__ cur,
        uint2* __restrict__ sp) {
    int t = blockIdx.x * 256 + threadIdx.x;
    if (t >= NT) return;
    int fb = flags[0];
    int c, n1, n2;
    if (flags[1]) {
        const long long* q = (const long long*)idxp;
        c = (int)q[3LL * t]; n1 = (int)q[3LL * t + 1]; n2 = (int)q[3LL * t + 2];
    } else {
        const int* q = (const int*)idxp;
        c = q[3 * t]; n1 = q[3 * t + 1]; n2 = q[3 * t + 2];
    }
    float d1 = ldf(d1p, t, fb);
    float d2 = ldf(d2p, t, fb);
    float asym = fabsf(d1 - d2) / (fmaxf(d1, d2) + 1e-8f);
    unsigned int qw = (unsigned int)((1.0f + 0.3f * asym) * WQUANT + 0.5f);
    if (qw > 32767u) qw = 32767u;
    uint2 m = make_uint2((unsigned int)n1 | (qw << 17), (unsigned int)n2);
    int pos = atomicAdd(&cur[c], 1);
    sp[pos] = m;
}

// ---------------------------------------------------------------------------
// accum (fallback only): one wave per center, segment from off[].
// ---------------------------------------------------------------------------
__global__ __launch_bounds__(256) void accum_kernel(
        const void* __restrict__ h, const int* __restrict__ flags,
        const __half* __restrict__ uh, const __half* __restrict__ vh,
        const int* __restrict__ seg, const uint2* __restrict__ sp,
        const void* __restrict__ gamma, const void* __restrict__ beta,
        void* __restrict__ out) {
    __shared__ uint2 metas[4][64];
    __shared__ float ucs[4][64];
    __shared__ float accs[4][HD];
    int tid = threadIdx.x, fb = flags[0];
    int wv = tid >> 6, lane = tid & 63;
    int n = blockIdx.x * 4 + wv;                  // NN % 4 == 0

    float hval = (lane < HD) ? ldf(h, (long long)n * HD + lane, fb) : 0.f;
    float uval = (lane < HD) ? __half2float(uh[(size_t)n * HD + lane]) : 0.f;
    ucs[wv][lane] = uval;                         // wave-sync write->read

    int s = lane >> 3, dg = lane & 7;
    hf2 uc4[4];
    #pragma unroll
    for (int j = 0; j < 4; ++j) {
        uc4[j].x = (_Float16)ucs[wv][dg * 8 + 2 * j];
        uc4[j].y = (_Float16)ucs[wv][dg * 8 + 2 * j + 1];
    }

    int start = (n == 0) ? 0 : seg[n - 1];
    int end = seg[n];
    float accf[8] = {0.f, 0.f, 0.f, 0.f, 0.f, 0.f, 0.f, 0.f};
    const char* vb = (const char*)vh;
    size_t dgo = (size_t)dg * 16;

    for (int chunk = start; chunk < end; chunk += 64) {
        int m = end - chunk; if (m > 64) m = 64;
        if (lane < m) metas[wv][lane] = sp[chunk + lane];
        for (int t = 0; t < m; t += 16) {
            uint2 m0 = metas[wv][t + s];
            uint2 m1 = metas[wv][t + 8 + s];
            int v0 = (t + s) < m, v1 = (t + 8 + s) < m;
            unsigned a0 = v0 ? (m0.x & 0x1FFFFu) : 0u;
            unsigned b0 = v0 ? (m0.y & 0x1FFFFu) : 0u;
            float w0 = v0 ? (float)(m0.x >> 17) * WSCALE : 0.f;
            unsigned a1 = v1 ? (m1.x & 0x1FFFFu) : 0u;
            unsigned b1 = v1 ? (m1.y & 0x1FFFFu) : 0u;
            float w1 = v1 ? (float)(m1.x >> 17) * WSCALE : 0.f;
            V4H pa0, pb0, pa1, pb1;
            pa0.u = *(const uint4*)(vb + (size_t)a0 * 128 + dgo);
            pb0.u = *(const uint4*)(vb + (size_t)b0 * 128 + dgo);
            pa1.u = *(const uint4*)(vb + (size_t)a1 * 128 + dgo);
            pb1.u = *(const uint4*)(vb + (size_t)b1 * 128 + dgo);
            hf2 aw0 = splat2(0.505f * w0), bw0 = splat2(0.495f * w0);
            hf2 aw1 = splat2(0.505f * w1), bw1 = splat2(0.495f * w1);
            #pragma unroll
            for (int j = 0; j < 4; ++j) {
                hf2 p0 = pa0.h[j] + pb0.h[j] + uc4[j];
                hf2 acch = p0 * aw0 + habs2(p0) * bw0;
                hf2 p1 = pa1.h[j] + pb1.h[j] + uc4[j];
                acch += p1 * aw1 + habs2(p1) * bw1;
                accf[2 * j]     += (float)acch.x;
                accf[2 * j + 1] += (float)acch.y;
            }
        }
    }

    #pragma unroll
    for (int j = 0; j < 8; ++j) {
        accf[j] += __shfl_xor(accf[j], 8, 64);
        accf[j] += __shfl_xor(accf[j], 16, 64);
        accf[j] += __shfl_xor(accf[j], 32, 64);
    }
    if (lane < 6) {
        #pragma unroll
        for (int j = 0; j < 8; ++j) accs[wv][lane * 8 + j] = accf[j];
    }
    float av = (lane < HD) ? accs[wv][lane] : 0.f;

    float rnc = rsqrtf(fmaxf((float)(end - start), 1.0f));
    float x = (lane < HD) ? (hval + av * rnc) : 0.f;
    float su = x, sq = x * x;
    #pragma unroll
    for (int o = 32; o; o >>= 1) {
        su += __shfl_xor(su, o, 64);
        sq += __shfl_xor(sq, o, 64);
    }
    float mu   = su * (1.0f / HD);
    float var  = sq * (1.0f / HD) - mu * mu;
    float rstd = rsqrtf(var + 1e-5f);
    if (lane < HD) {
        float g  = ldf(gamma, lane, fb);
        float bb = ldf(beta, lane, fb);
        float r = (x - mu) * rstd * g + bb;
        if (fb) ((__hip_bfloat16*)out)[(size_t)n * HD + lane] = __float2bfloat16(r);
        else    ((float*)out)[(size_t)n * HD + lane] = r;
    }
}

extern "C" void kernel_launch(void* const* d_in, const int* in_sizes, int n_in,
                              void* d_out, int out_size, void* d_ws, size_t ws_size,
                              hipStream_t stream) {
    const void* h     = d_in[0];
    const void* idx   = d_in[1];
    const void* d1    = d_in[2];
    const void* d2    = d_in[3];
    const void* W3    = d_in[4];
    const void* Wu    = d_in[5];
    const void* gamma = d_in[6];
    const void* beta  = d_in[7];

    char* base  = (char*)d_ws;
    int*   flags = (int*)base;                              // 64 B
    float* wu1f  = (float*)(base + 64);                     // 2304 f
    float* bf    = wu1f + HD * HD;                          // 2304 f
    uintptr_t ua = (uintptr_t)(bf + HD * HD);
    __half* uh   = (__half*)((ua + 127) & ~(uintptr_t)127); // NN*48 fp16 (9.6 MB)
    __half* vh   = (__half*)((char*)uh + (size_t)NN * HD * 2); // NN*64 fp16 (12.8 MB)
    char*  after = (char*)vh + (size_t)NN * VS * 2;

    // Primary (superbin) layout: gcur + binned after vh.
    int*   gcur = (int*)after;                              // NSB*32 ints (50 KB)
    uintptr_t bna = (uintptr_t)(gcur + (size_t)NSB * 32);
    uint2* binned = (uint2*)((bna + 127) & ~(uintptr_t)127); // NSB*SBCAP*8 = 19.2 MB
    size_t need_primary = ((char*)(binned + (size_t)NSB * SBCAP)) - base;

    // Fallback layout: cnt/off/bsum/sp after vh (R8 pipeline).
    int*   cnt  = (int*)after;                              // NN*16 ints (6.4 MB)
    int*   off  = (int*)(cnt + (size_t)NN * 16);            // NN
    int*   bsum = off + NN;                                 // NB (+pad)
    uintptr_t spa = (uintptr_t)(bsum + 256);
    uint2* sp   = (uint2*)((spa + 15) & ~(uintptr_t)15);    // NT uint2 (16 MB)

    prep_kernel<<<(HD * HD + 255) / 256, 256, 0, stream>>>(
        (const unsigned int*)h, (const unsigned int*)idx, flags, W3, Wu,
        wu1f, bf, gcur);

    if (ws_size >= need_primary) {
        // ---- superbin path: fused (node || scatter) + bucket/accum ----
        fused_nb_kernel<<<FATGRID, 1024, 0, stream>>>(
            h, flags, wu1f, bf, uh, vh, idx, d1, d2, gcur, binned);
        bin_accum_kernel<<<NBIN, 512, 0, stream>>>(h, flags, uh, vh, gcur, binned,
                                                   gamma, beta, d_out);
    } else {
        // ---- fallback: hist + scan + sorted scatter (R8 pipeline) ----
        node_kernel<<<NN / 16, 256, 0, stream>>>(h, flags, wu1f, bf, uh, vh);
        hipMemsetAsync(cnt, 0, (size_t)NN * 16 * sizeof(int), stream);
        hist_kernel<<<NBH, 256, 0, stream>>>(idx, flags, cnt);
        scan_part<<<NB, 1024, 0, stream>>>(cnt, off, bsum);
        scan_add<<<NB, 1024, 0, stream>>>(off, bsum);
        scatter_kernel<<<(NT + 255) / 256, 256, 0, stream>>>(
            idx, d1, d2, flags, off, sp);
        accum_kernel<<<NN / 4, 256, 0, stream>>>(h, flags, uh, vh, off, sp,
                                                 gamma, beta, d_out);
    }
}

// Round 10
// 266.769 us; speedup vs baseline: 1.2589x; 1.2589x over previous
//
#include <hip/hip_runtime.h>
#include <hip/hip_bf16.h>
#include <hip/hip_fp16.h>
#include <stdint.h>

#define NN 100000
#define NT 2000000
#define HD 48
#define VS 64                     // vh row stride in halfs (128 B, line-aligned)
#define CAP 56                    // per-center bucket capacity; P(Poisson(20) >= 56) ~ 4e-10
#define NPB 20                    // nodes per fused-node block (NN % 20 == 0)
#define NBH ((NT + 255) / 256)
#define NB ((NN + 1023) / 1024)   // 98 scan blocks (fallback)

// ---- coarse-bin pipeline (primary path) ----
#define BINB 64                       // centers per coarse bin
#define NBIN ((NN + BINB - 1) / BINB) // 1563
#define BINCAP 1792                   // metas/bin cap: mean 1280, sigma 35.8 -> +14.3σ
#define CHK 8192                      // triples per scatter block (run length ~5.2)
#define NCHK ((NT + CHK - 1) / CHK)   // 245
#define NNODEB (NN / NPB)             // 5000 node tiles
#define FATGRID (NCHK + NNODEB)       // scatter blocks first (long), node blocks fill

// weight encoding: w = qw * (1.3/32767); real triples give qw in [25206,32767].
#define WSCALE (1.3f / 32767.0f)
#define WQUANT (32767.0f / 1.3f)

typedef _Float16 hf2 __attribute__((ext_vector_type(2)));

__device__ __forceinline__ float b2f(__hip_bfloat16 x) { return __bfloat162float(x); }

// Load a "float tensor" element whose storage is bf16 (flag=1) or f32 (flag=0).
__device__ __forceinline__ float ldf(const void* p, long long i, int isbf16) {
    if (isbf16) return b2f(((const __hip_bfloat16*)p)[i]);
    return ((const float*)p)[i];
}

__device__ __forceinline__ hf2 habs2(hf2 x) {
    union { hf2 h; unsigned int u; } c; c.h = x; c.u &= 0x7FFF7FFFu; return c.h;
}
__device__ __forceinline__ hf2 splat2(float f) {
    hf2 r; r.x = (_Float16)f; r.y = (_Float16)f; return r;
}
union V4H { uint4 u; hf2 h[4]; };

// ---------------------------------------------------------------------------
// prep (9 blocks): self-probe dtypes, fold weights, zero gcur.
// wu1f[o][k] = Wu[o][k];  bf[o][k] = sum_j Wu[o][48+j] * W3[j][k]
// ---------------------------------------------------------------------------
__global__ __launch_bounds__(256) void prep_kernel(
        const unsigned int* __restrict__ hw, const unsigned int* __restrict__ iw,
        int* __restrict__ flags,
        const void* __restrict__ W3, const void* __restrict__ Wu,
        float* __restrict__ wu1f, float* __restrict__ bf,
        int* __restrict__ gcur) {
    __shared__ int cbf, cix;
    int tid = threadIdx.x;
    if (tid == 0) { cbf = 0; cix = 0; }
    __syncthreads();
    unsigned int e = (hw[tid] >> 7) & 0xff;       // exponent of low-half bf16
    if (e >= 90 && e <= 144) atomicAdd(&cbf, 1);
    if (blockIdx.x == 0 && iw[2 * tid + 1] == 0) atomicAdd(&cix, 1);
    __syncthreads();
    int fb = (cbf >= 192) ? 1 : 0;                // bf16 ~256 hits; f32 ~55
    if (blockIdx.x == 0 && tid == 0) {
        flags[0] = fb;
        flags[1] = (cix >= 255) ? 1 : 0;          // int64 high words all zero
    }
    for (int i = blockIdx.x * 256 + tid; i < NBIN * 32; i += 9 * 256)
        gcur[i] = 0;
    int i = blockIdx.x * 256 + tid;
    if (i < HD * HD) {
        int o = i / HD, hh = i % HD;
        wu1f[i] = ldf(Wu, o * 2 * HD + hh, fb);
        float s = 0.f;
        #pragma unroll 8
        for (int k = 0; k < HD; ++k)
            s += ldf(Wu, o * 2 * HD + HD + k, fb) * ldf(W3, k * HD + hh, fb);
        bf[i] = s;
    }
}

// ---------------------------------------------------------------------------
// fused_nb (primary): scatter and node-transform are DATA-INDEPENDENT; one
// fat kernel runs both. Blocks 0..NCHK-1 = scatter chunks (long, start
// first); blocks NCHK.. = 20-node tiles filling the rest.
//
// scatter part: two-phase block-aggregated binning (the R9 single-phase
// global-atomic form regressed to run-length-1 writes, 134MB writeback --
// block aggregation is what creates write locality). R7/R8 lesson: metas
// held in REGISTERS across the two barriers get demoted to scratch
// (VGPR 20-24 < 32 live values, WRITE 72-95MB varying). Fix: cross-barrier
// bulk state lives in LDS. Phase 1: decode -> meta to L.b.metas[slot]
// (linear, conflict-free) + rank from LDS atomic, keep ONLY packed
// bn|rk<<11 in 8 named registers. Reserve: one global atomic per
// (block, non-empty bin). Phase 2: read meta back from LDS, store at
// gb[bn]+rk. LDS 78KB -> 2 blocks/CU (32 waves).
// meta: x = n1 | qw15<<17 ; y = n2 | (c&63)<<17
//
// node part: u[n]=Wu1*h[n] (fp16 stride-48), v[n]=M*h[n] (fp16 stride-64 =
// 128 B line-aligned rows, dims 48..63 zeroed so gathers are single-line).
// ---------------------------------------------------------------------------
struct NodeLds { float Ws[HD * 49]; float Bs[HD * 49]; float hs[NPB * HD]; };
struct BinLds  { int h1[NBIN]; int gb[NBIN]; uint2 metas[CHK]; };
union FatLds   { NodeLds n; BinLds b; };

#define DECODE(J)                                                             \
    unsigned bnrk##J = 0xFFFFFFFFu;                                           \
    {                                                                         \
        int t = t0 + (J) * 1024 + tid;                                        \
        if (t < NT) {                                                         \
            int c, n1, n2;                                                    \
            if (fi) {                                                         \
                c  = qi[6LL * t];                                             \
                n1 = qi[6LL * t + 2];                                         \
                n2 = qi[6LL * t + 4];                                         \
            } else {                                                          \
                c  = qi[3LL * t];                                             \
                n1 = qi[3LL * t + 1];                                         \
                n2 = qi[3LL * t + 2];                                         \
            }                                                                 \
            float d1 = ldf(d1p, t, fb);                                       \
            float d2 = ldf(d2p, t, fb);                                       \
            float asym = fabsf(d1 - d2) / (fmaxf(d1, d2) + 1e-8f);            \
            unsigned qw = (unsigned)((1.0f + 0.3f * asym) * WQUANT + 0.5f);   \
            if (qw > 32767u) qw = 32767u;                                     \
            int bn = c >> 6;                                                  \
            int rk = atomicAdd(&L.b.h1[bn], 1);                               \
            bnrk##J = (unsigned)bn | ((unsigned)rk << 11);                    \
            L.b.metas[(J) * 1024 + tid] =                                     \
                make_uint2((unsigned)n1 | (qw << 17),                         \
                           (unsigned)n2 | ((unsigned)(c & 63) << 17));        \
        }                                                                     \
    }

#define SCAT(J)                                                               \
    if (bnrk##J != 0xFFFFFFFFu) {                                             \
        int bn = (int)(bnrk##J & 2047u);                                      \
        int rk = (int)(bnrk##J >> 11);                                        \
        int pos = L.b.gb[bn] + rk;                                            \
        if (pos < BINCAP)                                                     \
            binned[(size_t)bn * BINCAP + pos] = L.b.metas[(J) * 1024 + tid];  \
    }

__global__ __launch_bounds__(1024) void fused_nb_kernel(
        const void* __restrict__ h, const int* __restrict__ flags,
        const float* __restrict__ wu1f, const float* __restrict__ bf,
        __half* __restrict__ uh, __half* __restrict__ vh,
        const void* __restrict__ idxp,
        const void* __restrict__ d1p, const void* __restrict__ d2p,
        int* __restrict__ gcur, uint2* __restrict__ binned) {
    __shared__ FatLds L;
    int tid = threadIdx.x;
    int fb = flags[0];

    if (blockIdx.x < NCHK) {
        // ---------------- scatter part ----------------
        int fi = flags[1];
        for (int i = tid; i < NBIN; i += 1024) L.b.h1[i] = 0;
        __syncthreads();
        int t0 = blockIdx.x * CHK;
        const int* qi = (const int*)idxp;         // int64: low words at even idx

        // phase 1: decode -> LDS meta + LDS-atomic rank; 8 packed regs live
        DECODE(0) DECODE(1) DECODE(2) DECODE(3)
        DECODE(4) DECODE(5) DECODE(6) DECODE(7)
        __syncthreads();
        for (int b = tid; b < NBIN; b += 1024) {  // reserve contiguous runs
            int n = L.b.h1[b];
            L.b.gb[b] = n ? atomicAdd(&gcur[b << 5], n) : 0;
        }
        __syncthreads();
        // phase 2: metas from LDS -> global at gb + rank
        SCAT(0) SCAT(1) SCAT(2) SCAT(3)
        SCAT(4) SCAT(5) SCAT(6) SCAT(7)
    } else {
        // ---------------- node part ----------------
        int base = (blockIdx.x - NCHK) * NPB;     // NN % 20 == 0
        for (int i = tid; i < HD * HD; i += 1024) {
            int o = i / HD, hh = i % HD;
            L.n.Ws[o * 49 + hh] = wu1f[i];
            L.n.Bs[o * 49 + hh] = bf[i];
        }
        for (int i = tid; i < NPB * HD; i += 1024)
            L.n.hs[i] = ldf(h, (long long)base * HD + i, fb);
        if (tid < NPB * 16) {  // zero the vh pad dims 48..63
            int ln = tid >> 4, o = HD + (tid & 15);
            vh[(size_t)(base + ln) * VS + o] = (__half)0.f;
        }
        __syncthreads();
        for (int i = tid; i < NPB * HD; i += 1024) {
            int ln = i / HD, o = i - ln * HD;
            const float* hr = L.n.hs + ln * HD;
            const float* wr = L.n.Ws + o * 49;
            const float* br = L.n.Bs + o * 49;
            float su = 0.f, sv = 0.f;
            #pragma unroll
            for (int k = 0; k < HD; ++k) { float hv = hr[k]; su += wr[k] * hv; sv += br[k] * hv; }
            int n = base + ln;
            uh[(size_t)n * HD + o] = __float2half(su);
            vh[(size_t)n * VS + o] = __float2half(sv);
        }
    }
}

// ---------------------------------------------------------------------------
// bin_accum (primary): one block per 64-center bin. Coalesced read of the
// bin's metas, LDS-atomic scatter into per-center LDS buckets (rows padded
// to 64 so the t+8+s probe stays in-row), then the proven per-wave accum
// (R5 form: 16 triples/trip, FOUR gathers issued back-to-back; validity
// selects give w=0/row-0 for tail slots): lane=(s 0..7, dg 0..7),
// single-line uint4 gathers of 8 fp16 dims, packed-fp16
// leaky(p)*w = (.505w)p + (.495w)|p|, drained to f32 per 16 triples.
// Fused residual + LayerNorm epilogue. 8 waves x 8 centers each.
// LDS = 36.6 KB -> 4 blocks/CU (32 waves/CU).
// NOTE (R3/R6 post-mortems): do NOT hand-pipeline (R3: 79->105us) and do
// NOT widen to 32-trip/8-gather (R6: 78.6->81.5us, VGPR 40, Occ -11pts).
// The 16-trip straight-line 4-gather block is a verified local optimum.
// ---------------------------------------------------------------------------
__global__ __launch_bounds__(512, 4) void bin_accum_kernel(
        const void* __restrict__ h, const int* __restrict__ flags,
        const __half* __restrict__ uh, const __half* __restrict__ vh,
        const int* __restrict__ gcur, const uint2* __restrict__ binned,
        const void* __restrict__ gamma, const void* __restrict__ beta,
        void* __restrict__ out) {
    __shared__ uint2 buckets[BINB][64];           // 32768 B, 56 slots used
    __shared__ int   cur[BINB];
    __shared__ float ucs[8][64];
    __shared__ float accs[8][HD];
    int tid = threadIdx.x, fb = flags[0];
    int bin = blockIdx.x;

    for (int i = tid; i < BINB; i += 512) cur[i] = 0;
    __syncthreads();

    int nm = gcur[bin << 5]; if (nm > BINCAP) nm = BINCAP;
    const uint2* bp = binned + (size_t)bin * BINCAP;
    for (int i = tid; i < nm; i += 512) {         // LDS bucket scatter
        uint2 m = bp[i];
        int cl = (m.y >> 17) & (BINB - 1);
        int r = atomicAdd(&cur[cl], 1);
        if (r < CAP) buckets[cl][r] = m;
    }
    __syncthreads();

    int wv = tid >> 6, lane = tid & 63;
    int s = lane >> 3, dg = lane & 7;
    const char* vb = (const char*)vh;
    size_t dgo = (size_t)dg * 16;
    float gv = (lane < HD) ? ldf(gamma, lane, fb) : 0.f;
    float bv = (lane < HD) ? ldf(beta, lane, fb) : 0.f;

    for (int ci = 0; ci < BINB / 8; ++ci) {       // 8 centers per wave
        int cl = wv * (BINB / 8) + ci;
        int n = bin * BINB + cl;
        if (n >= NN) continue;                    // last bin: tail centers

        int m = cur[cl]; if (m > CAP) m = CAP;
        float hval = (lane < HD) ? ldf(h, (long long)n * HD + lane, fb) : 0.f;
        float uval = (lane < HD) ? __half2float(uh[(size_t)n * HD + lane]) : 0.f;
        ucs[wv][lane] = uval;                     // wave-sync write->read
        hf2 uc4[4];
        #pragma unroll
        for (int j = 0; j < 4; ++j) {
            uc4[j].x = (_Float16)ucs[wv][dg * 8 + 2 * j];
            uc4[j].y = (_Float16)ucs[wv][dg * 8 + 2 * j + 1];
        }

        float accf[8] = {0.f, 0.f, 0.f, 0.f, 0.f, 0.f, 0.f, 0.f};
        for (int t = 0; t < m; t += 16) {
            uint2 m0 = buckets[cl][t + s];        // in padded row, LDS-safe
            uint2 m1 = buckets[cl][t + 8 + s];
            int v0 = (t + s) < m, v1 = (t + 8 + s) < m;
            unsigned a0 = v0 ? (m0.x & 0x1FFFFu) : 0u;
            unsigned b0 = v0 ? (m0.y & 0x1FFFFu) : 0u;
            float w0 = v0 ? (float)(m0.x >> 17) * WSCALE : 0.f;
            unsigned a1 = v1 ? (m1.x & 0x1FFFFu) : 0u;
            unsigned b1 = v1 ? (m1.y & 0x1FFFFu) : 0u;
            float w1 = v1 ? (float)(m1.x >> 17) * WSCALE : 0.f;
            V4H pa0, pb0, pa1, pb1;
            pa0.u = *(const uint4*)(vb + (size_t)a0 * 128 + dgo);
            pb0.u = *(const uint4*)(vb + (size_t)b0 * 128 + dgo);
            pa1.u = *(const uint4*)(vb + (size_t)a1 * 128 + dgo);
            pb1.u = *(const uint4*)(vb + (size_t)b1 * 128 + dgo);
            hf2 aw0 = splat2(0.505f * w0), bw0 = splat2(0.495f * w0);
            hf2 aw1 = splat2(0.505f * w1), bw1 = splat2(0.495f * w1);
            #pragma unroll
            for (int j = 0; j < 4; ++j) {
                hf2 p0 = pa0.h[j] + pb0.h[j] + uc4[j];
                hf2 acch = p0 * aw0 + habs2(p0) * bw0;
                hf2 p1 = pa1.h[j] + pb1.h[j] + uc4[j];
                acch += p1 * aw1 + habs2(p1) * bw1;
                accf[2 * j]     += (float)acch.x;
                accf[2 * j + 1] += (float)acch.y;
            }
        }

        // reduce across the 8 slot-copies (lane bits 3..5)
        #pragma unroll
        for (int j = 0; j < 8; ++j) {
            accf[j] += __shfl_xor(accf[j], 8, 64);
            accf[j] += __shfl_xor(accf[j], 16, 64);
            accf[j] += __shfl_xor(accf[j], 32, 64);
        }
        if (lane < 6) {                           // dims 0..47
            #pragma unroll
            for (int j = 0; j < 8; ++j) accs[wv][lane * 8 + j] = accf[j];
        }
        float av = (lane < HD) ? accs[wv][lane] : 0.f; // wave-sync

        float rnc = rsqrtf(fmaxf((float)m, 1.0f));
        float x = (lane < HD) ? (hval + av * rnc) : 0.f;
        float su = x, sq = x * x;
        #pragma unroll
        for (int o = 32; o; o >>= 1) {
            su += __shfl_xor(su, o, 64);
            sq += __shfl_xor(sq, o, 64);
        }
        float mu   = su * (1.0f / HD);
        float var  = sq * (1.0f / HD) - mu * mu;
        float rstd = rsqrtf(var + 1e-5f);
        if (lane < HD) {
            float r = (x - mu) * rstd * gv + bv;
            if (fb) ((__hip_bfloat16*)out)[(size_t)n * HD + lane] = __float2bfloat16(r);
            else    ((float*)out)[(size_t)n * HD + lane] = r;
        }
    }
}

// ---------------------------------------------------------------------------
// node (fallback only): u[n]=Wu1*h[n], v[n]=M*h[n].
// ---------------------------------------------------------------------------
__global__ __launch_bounds__(256) void node_kernel(
        const void* __restrict__ h, const int* __restrict__ flags,
        const float* __restrict__ wu1f, const float* __restrict__ bf,
        __half* __restrict__ uh, __half* __restrict__ vh) {
    __shared__ float Ws[HD * 49];
    __shared__ float Bs[HD * 49];
    __shared__ float hs[16 * HD];
    int tid = threadIdx.x;
    int fb = flags[0];
    for (int i = tid; i < HD * HD; i += 256) {
        int o = i / HD, hh = i % HD;
        Ws[o * 49 + hh] = wu1f[i];
        Bs[o * 49 + hh] = bf[i];
    }
    int base = blockIdx.x * 16;                   // NN % 16 == 0
    for (int i = tid; i < 16 * HD; i += 256)
        hs[i] = ldf(h, (long long)base * HD + i, fb);
    {   // zero the vh pad dims 48..63
        int ln = tid >> 4, o = HD + (tid & 15);
        vh[(size_t)(base + ln) * VS + o] = (__half)0.f;
    }
    __syncthreads();
    for (int i = tid; i < 16 * HD; i += 256) {
        int ln = i / HD, o = i - ln * HD;
        const float* hr = hs + ln * HD;
        const float* wr = Ws + o * 49;
        const float* br = Bs + o * 49;
        float su = 0.f, sv = 0.f;
        #pragma unroll
        for (int k = 0; k < HD; ++k) { float hv = hr[k]; su += wr[k] * hv; sv += br[k] * hv; }
        int n = base + ln;
        uh[(size_t)n * HD + o] = __float2half(su);
        vh[(size_t)n * VS + o] = __float2half(sv);
    }
}

// ---------------------------------------------------------------------------
// hist (fallback only): line-padded counters cnt[c<<4].
// ---------------------------------------------------------------------------
__global__ __launch_bounds__(256) void hist_kernel(const void* __restrict__ idxp,
                                                   const int* __restrict__ flags,
                                                   int* __restrict__ cnt) {
    int t = blockIdx.x * 256 + threadIdx.x;
    if (t >= NT) return;
    int c = flags[1] ? (int)((const long long*)idxp)[3LL * t]
                     : ((const int*)idxp)[3 * t];
    atomicAdd(&cnt[c << 4], 1);
}

// ---------------------------------------------------------------------------
// scans (fallback only): exclusive scan of cnt[i<<4] -> off[NN].
// ---------------------------------------------------------------------------
__global__ __launch_bounds__(1024) void scan_part(const int* __restrict__ cnt,
                                                  int* __restrict__ off,
                                                  int* __restrict__ bsum) {
    __shared__ int wsums[16];
    int tid = threadIdx.x, lane = tid & 63, wv = tid >> 6;
    int i = blockIdx.x * 1024 + tid;
    int x = (i < NN) ? cnt[i << 4] : 0;
    int vx = x;
    #pragma unroll
    for (int o = 1; o < 64; o <<= 1) {
        int y = __shfl_up(vx, o, 64);
        if (lane >= o) vx += y;
    }
    if (lane == 63) wsums[wv] = vx;
    __syncthreads();
    if (tid == 0) {
        int s = 0;
        #pragma unroll
        for (int k = 0; k < 16; ++k) { int t2 = wsums[k]; wsums[k] = s; s += t2; }
        bsum[blockIdx.x] = s;
    }
    __syncthreads();
    if (i < NN) off[i] = wsums[wv] + vx - x;
}

__global__ __launch_bounds__(1024) void scan_add(int* __restrict__ off,
                                                 const int* __restrict__ bsum) {
    int bid = blockIdx.x;
    int pre = 0;
    for (int k = 0; k < bid; ++k) pre += bsum[k];
    int i = bid * 1024 + threadIdx.x;
    if (i < NN) off[i] += pre;
}

// ---------------------------------------------------------------------------
// scatter (fallback only): meta = uint2{ n1 | qw<<17, n2 }.
// pos = atomicAdd(&off[c],1)  (off -> inclusive end)
// ---------------------------------------------------------------------------
__global__ __launch_bounds__(256) void scatter_kernel(
        const void* __restrict__ idxp,
        const void* __restrict__ d1p, const void* __restrict__ d2p,
        const int* __restrict__ flags, int* __restrict__ cur,
        uint2* __restrict__ sp) {
    int t = blockIdx.x * 256 + threadIdx.x;
    if (t >= NT) return;
    int fb = flags[0];
    int c, n1, n2;
    if (flags[1]) {
        const long long* q = (const long long*)idxp;
        c = (int)q[3LL * t]; n1 = (int)q[3LL * t + 1]; n2 = (int)q[3LL * t + 2];
    } else {
        const int* q = (const int*)idxp;
        c = q[3 * t]; n1 = q[3 * t + 1]; n2 = q[3 * t + 2];
    }
    float d1 = ldf(d1p, t, fb);
    float d2 = ldf(d2p, t, fb);
    float asym = fabsf(d1 - d2) / (fmaxf(d1, d2) + 1e-8f);
    unsigned int qw = (unsigned int)((1.0f + 0.3f * asym) * WQUANT + 0.5f);
    if (qw > 32767u) qw = 32767u;
    uint2 m = make_uint2((unsigned int)n1 | (qw << 17), (unsigned int)n2);
    int pos = atomicAdd(&cur[c], 1);
    sp[pos] = m;
}

// ---------------------------------------------------------------------------
// accum (fallback only): one wave per center, segment from off[].
// ---------------------------------------------------------------------------
__global__ __launch_bounds__(256) void accum_kernel(
        const void* __restrict__ h, const int* __restrict__ flags,
        const __half* __restrict__ uh, const __half* __restrict__ vh,
        const int* __restrict__ seg, const uint2* __restrict__ sp,
        const void* __restrict__ gamma, const void* __restrict__ beta,
        void* __restrict__ out) {
    __shared__ uint2 metas[4][64];
    __shared__ float ucs[4][64];
    __shared__ float accs[4][HD];
    int tid = threadIdx.x, fb = flags[0];
    int wv = tid >> 6, lane = tid & 63;
    int n = blockIdx.x * 4 + wv;                  // NN % 4 == 0

    float hval = (lane < HD) ? ldf(h, (long long)n * HD + lane, fb) : 0.f;
    float uval = (lane < HD) ? __half2float(uh[(size_t)n * HD + lane]) : 0.f;
    ucs[wv][lane] = uval;                         // wave-sync write->read

    int s = lane >> 3, dg = lane & 7;
    hf2 uc4[4];
    #pragma unroll
    for (int j = 0; j < 4; ++j) {
        uc4[j].x = (_Float16)ucs[wv][dg * 8 + 2 * j];
        uc4[j].y = (_Float16)ucs[wv][dg * 8 + 2 * j + 1];
    }

    int start = (n == 0) ? 0 : seg[n - 1];
    int end = seg[n];
    float accf[8] = {0.f, 0.f, 0.f, 0.f, 0.f, 0.f, 0.f, 0.f};
    const char* vb = (const char*)vh;
    size_t dgo = (size_t)dg * 16;

    for (int chunk = start; chunk < end; chunk += 64) {
        int m = end - chunk; if (m > 64) m = 64;
        if (lane < m) metas[wv][lane] = sp[chunk + lane];
        for (int t = 0; t < m; t += 16) {
            uint2 m0 = metas[wv][t + s];
            uint2 m1 = metas[wv][t + 8 + s];
            int v0 = (t + s) < m, v1 = (t + 8 + s) < m;
            unsigned a0 = v0 ? (m0.x & 0x1FFFFu) : 0u;
            unsigned b0 = v0 ? (m0.y & 0x1FFFFu) : 0u;
            float w0 = v0 ? (float)(m0.x >> 17) * WSCALE : 0.f;
            unsigned a1 = v1 ? (m1.x & 0x1FFFFu) : 0u;
            unsigned b1 = v1 ? (m1.y & 0x1FFFFu) : 0u;
            float w1 = v1 ? (float)(m1.x >> 17) * WSCALE : 0.f;
            V4H pa0, pb0, pa1, pb1;
            pa0.u = *(const uint4*)(vb + (size_t)a0 * 128 + dgo);
            pb0.u = *(const uint4*)(vb + (size_t)b0 * 128 + dgo);
            pa1.u = *(const uint4*)(vb + (size_t)a1 * 128 + dgo);
            pb1.u = *(const uint4*)(vb + (size_t)b1 * 128 + dgo);
            hf2 aw0 = splat2(0.505f * w0), bw0 = splat2(0.495f * w0);
            hf2 aw1 = splat2(0.505f * w1), bw1 = splat2(0.495f * w1);
            #pragma unroll
            for (int j = 0; j < 4; ++j) {
                hf2 p0 = pa0.h[j] + pb0.h[j] + uc4[j];
                hf2 acch = p0 * aw0 + habs2(p0) * bw0;
                hf2 p1 = pa1.h[j] + pb1.h[j] + uc4[j];
                acch += p1 * aw1 + habs2(p1) * bw1;
                accf[2 * j]     += (float)acch.x;
                accf[2 * j + 1] += (float)acch.y;
            }
        }
    }

    #pragma unroll
    for (int j = 0; j < 8; ++j) {
        accf[j] += __shfl_xor(accf[j], 8, 64);
        accf[j] += __shfl_xor(accf[j], 16, 64);
        accf[j] += __shfl_xor(accf[j], 32, 64);
    }
    if (lane < 6) {
        #pragma unroll
        for (int j = 0; j < 8; ++j) accs[wv][lane * 8 + j] = accf[j];
    }
    float av = (lane < HD) ? accs[wv][lane] : 0.f;

    float rnc = rsqrtf(fmaxf((float)(end - start), 1.0f));
    float x = (lane < HD) ? (hval + av * rnc) : 0.f;
    float su = x, sq = x * x;
    #pragma unroll
    for (int o = 32; o; o >>= 1) {
        su += __shfl_xor(su, o, 64);
        sq += __shfl_xor(sq, o, 64);
    }
    float mu   = su * (1.0f / HD);
    float var  = sq * (1.0f / HD) - mu * mu;
    float rstd = rsqrtf(var + 1e-5f);
    if (lane < HD) {
        float g  = ldf(gamma, lane, fb);
        float bb = ldf(beta, lane, fb);
        float r = (x - mu) * rstd * g + bb;
        if (fb) ((__hip_bfloat16*)out)[(size_t)n * HD + lane] = __float2bfloat16(r);
        else    ((float*)out)[(size_t)n * HD + lane] = r;
    }
}

extern "C" void kernel_launch(void* const* d_in, const int* in_sizes, int n_in,
                              void* d_out, int out_size, void* d_ws, size_t ws_size,
                              hipStream_t stream) {
    const void* h     = d_in[0];
    const void* idx   = d_in[1];
    const void* d1    = d_in[2];
    const void* d2    = d_in[3];
    const void* W3    = d_in[4];
    const void* Wu    = d_in[5];
    const void* gamma = d_in[6];
    const void* beta  = d_in[7];

    char* base  = (char*)d_ws;
    int*   flags = (int*)base;                              // 64 B
    float* wu1f  = (float*)(base + 64);                     // 2304 f
    float* bf    = wu1f + HD * HD;                          // 2304 f
    uintptr_t ua = (uintptr_t)(bf + HD * HD);
    __half* uh   = (__half*)((ua + 127) & ~(uintptr_t)127); // NN*48 fp16 (9.6 MB)
    __half* vh   = (__half*)((char*)uh + (size_t)NN * HD * 2); // NN*64 fp16 (12.8 MB)
    char*  after = (char*)vh + (size_t)NN * VS * 2;

    // Primary (coarse-bin) layout: gcur + binned after vh.
    int*   gcur = (int*)after;                              // NBIN*32 ints (200 KB)
    uintptr_t bna = (uintptr_t)(gcur + (size_t)NBIN * 32);
    uint2* binned = (uint2*)((bna + 127) & ~(uintptr_t)127); // NBIN*BINCAP*8 = 22.4 MB
    size_t need_primary = ((char*)(binned + (size_t)NBIN * BINCAP)) - base;

    // Fallback layout: cnt/off/bsum/sp after vh (R8 pipeline).
    int*   cnt  = (int*)after;                              // NN*16 ints (6.4 MB)
    int*   off  = (int*)(cnt + (size_t)NN * 16);            // NN
    int*   bsum = off + NN;                                 // NB (+pad)
    uintptr_t spa = (uintptr_t)(bsum + 256);
    uint2* sp   = (uint2*)((spa + 15) & ~(uintptr_t)15);    // NT uint2 (16 MB)

    prep_kernel<<<(HD * HD + 255) / 256, 256, 0, stream>>>(
        (const unsigned int*)h, (const unsigned int*)idx, flags, W3, Wu,
        wu1f, bf, gcur);

    if (ws_size >= need_primary) {
        // ---- coarse-bin path: fused (node || scatter) + bucket/accum ----
        fused_nb_kernel<<<FATGRID, 1024, 0, stream>>>(
            h, flags, wu1f, bf, uh, vh, idx, d1, d2, gcur, binned);
        bin_accum_kernel<<<NBIN, 512, 0, stream>>>(h, flags, uh, vh, gcur, binned,
                                                   gamma, beta, d_out);
    } else {
        // ---- fallback: hist + scan + sorted scatter (R8 pipeline) ----
        node_kernel<<<NN / 16, 256, 0, stream>>>(h, flags, wu1f, bf, uh, vh);
        hipMemsetAsync(cnt, 0, (size_t)NN * 16 * sizeof(int), stream);
        hist_kernel<<<NBH, 256, 0, stream>>>(idx, flags, cnt);
        scan_part<<<NB, 1024, 0, stream>>>(cnt, off, bsum);
        scan_add<<<NB, 1024, 0, stream>>>(off, bsum);
        scatter_kernel<<<(NT + 255) / 256, 256, 0, stream>>>(
            idx, d1, d2, flags, off, sp);
        accum_kernel<<<NN / 4, 256, 0, stream>>>(h, flags, uh, vh, off, sp,
                                                 gamma, beta, d_out);
    }
}